// Round 4
// baseline (474.882 us; speedup 1.0000x reference)
//
#include <hip/hip_runtime.h>
#include <hip/hip_bf16.h>

// Sizes from the reference
#define B_  16
#define N_  256
#define L_  64
#define H_  32
#define HE_ 128
#define EO_ 64

typedef __attribute__((ext_vector_type(8))) short bf16x8;
typedef __attribute__((ext_vector_type(4))) float f32x4;

__device__ __forceinline__ unsigned cvt_pk_bf16(float a, float b) {
  unsigned r;
  asm("v_cvt_pk_bf16_f32 %0, %1, %2" : "=v"(r) : "v"(a), "v"(b));
  return r;
}
// abs folded as VOP3 input modifiers — saves the separate v_and per element
__device__ __forceinline__ unsigned cvt_pk_bf16_abs(float a, float b) {
  unsigned r;
  asm("v_cvt_pk_bf16_f32 %0, |%1|, |%2|" : "=v"(r) : "v"(a), "v"(b));
  return r;
}

// async global->LDS, 16B per lane; LDS dest must be wave-uniform base + lane*16
#define GLD_LDS16(gp, lp)                                                        \
  __builtin_amdgcn_global_load_lds(                                              \
      (const __attribute__((address_space(1))) unsigned int*)(gp),               \
      (__attribute__((address_space(3))) unsigned int*)(lp), 16, 0, 0)

// ---------------------------------------------------------------------------
// Setup (once): Wp = 0.6*We1[:H]@We2, Wq = 0.6*We1[H:]@We2,
// bp = 0.6*be1@We2 + be2, and Bfrag = 0.4*We2 in bf16 MFMA B-fragment layout.
// grid (8,3), block 256
// ---------------------------------------------------------------------------
__global__ void k_setup(const float* __restrict__ We1, const float* __restrict__ be1,
                        const float* __restrict__ We2, const float* __restrict__ be2,
                        float* __restrict__ Wp, float* __restrict__ Wq,
                        float* __restrict__ bp, uint4* __restrict__ Bfrag) {
  const int t   = blockIdx.y;
  const int gid = blockIdx.x * 256 + threadIdx.x;   // 0..2047
  const float* We1t = We1 + t * 64 * 128;
  const float* We2t = We2 + t * 128 * 64;

  { // Wp / Wq: 32x64 outputs each
    int f = gid >> 6, o = gid & 63;
    float ap = 0.f, aq = 0.f;
    for (int k = 0; k < 128; ++k) {
      float w2 = We2t[k * 64 + o];
      ap += We1t[f * 128 + k] * w2;
      aq += We1t[(32 + f) * 128 + k] * w2;
    }
    Wp[(t * 32 + f) * 64 + o] = 0.6f * ap;
    Wq[(t * 32 + f) * 64 + o] = 0.6f * aq;
  }
  if (gid < 64) {
    float ab = be2[t * 64 + gid];
    for (int k = 0; k < 128; ++k) ab += 0.6f * be1[t * 128 + k] * We2t[k * 64 + gid];
    bp[t * 64 + gid] = ab;
  }
  // Bfrag: 1024 uint4 per t; frag map: k = kk*32 + (lane>>4)*8 + e, o = nt*16 + (lane&15)
  if (gid < 1024) {
    int u = gid;
    int kk = u >> 8, nt = (u >> 6) & 3, ln = u & 63;
    int k0 = kk * 32 + (ln >> 4) * 8, o = nt * 16 + (ln & 15);
    unsigned w[4];
#pragma unroll
    for (int p = 0; p < 4; ++p) {
      float v0 = 0.4f * We2t[(k0 + 2 * p) * 64 + o];
      float v1 = 0.4f * We2t[(k0 + 2 * p + 1) * 64 + o];
      w[p] = cvt_pk_bf16(v0, v1);
    }
    Bfrag[t * 1024 + u] = make_uint4(w[0], w[1], w[2], w[3]);
  }
}

// ---------------------------------------------------------------------------
// Init + proj(t=0), fused: h = (x@W_lin+b_lin)@W_in+b_in, then
// R' = h@We1[:H]+be1, S = h@We1[H:], P = h@Wp+bp, Q = h@Wq  (t=0, write set 0).
// grid 1024, block 256 (one wave per (b,n) row)
// ---------------------------------------------------------------------------
__global__ __launch_bounds__(256) void k_init_proj(
    const float* __restrict__ x, const float* __restrict__ W_lin,
    const float* __restrict__ b_lin, const float* __restrict__ W_in,
    const float* __restrict__ b_in,
    const float* __restrict__ We1, const float* __restrict__ be1,
    const float* __restrict__ Wp, const float* __restrict__ Wq,
    const float* __restrict__ bp,
    float* __restrict__ h, float* __restrict__ Rp, float* __restrict__ S,
    float* __restrict__ P, float* __restrict__ Q) {
  __shared__ float sm[4][64];
  __shared__ float hs[4][33];
  const int w = threadIdx.x >> 6, lane = threadIdx.x & 63;
  const int row = __builtin_amdgcn_readfirstlane(blockIdx.x * 4 + w);
  const int b = row >> 8, n = row & 255;
  float acc = b_lin[n * 64 + lane];
  const float* xb = x + b * 64;
  for (int l = 0; l < 64; ++l)
    acc += xb[l] * W_lin[l * (N_ * L_) + n * 64 + lane];
  sm[w][lane] = acc;
  __syncthreads();
  if (lane < 32) {
    float hacc = b_in[lane];
#pragma unroll 8
    for (int f = 0; f < 64; ++f) hacc += sm[w][f] * W_in[f * 32 + lane];
    h[row * 32 + lane] = hacc;
    hs[w][lane] = hacc;
  }
  __syncthreads();

  // proj for t=0, h from LDS
  float r0 = be1[lane], r1 = be1[64 + lane];
  float s0 = 0.f, s1 = 0.f;
  float p = bp[lane], q = 0.f;
  for (int f = 0; f < 32; ++f) {
    float hf = hs[w][f];
    r0 += hf * We1[f * 128 + lane];
    r1 += hf * We1[f * 128 + 64 + lane];
    s0 += hf * We1[(32 + f) * 128 + lane];
    s1 += hf * We1[(32 + f) * 128 + 64 + lane];
    p  += hf * Wp[f * 64 + lane];
    q  += hf * Wq[f * 64 + lane];
  }
  Rp[row * 128 + lane] = r0;  Rp[row * 128 + 64 + lane] = r1;
  S [row * 128 + lane] = s0;  S [row * 128 + 64 + lane] = s1;
  P [row * 64 + lane]  = p;   Q [row * 64 + lane]       = q;
}

// ---------------------------------------------------------------------------
// Fused per-round kernel: edge-MLP over ALL j + aggregate + node MLP +
// proj(t+1). grid 256 = (b, 16-row i-tile); block 1024 (16 waves, 4/SIMD).
// Every wave owns the same 16i x 64o m-tile and processes 4 j per 64-j chunk;
// S/Q chunks are double-buffered in LDS via global_load_lds (each global line
// fetched exactly once per block -> structural dedup, no L2 herd).
// Rp/S/P/Q are round-double-buffered (read set, write set) to avoid the
// cross-block WAR race that fusing proj would otherwise create.
// LDS floats: SB[2]@0/8192, QB[2]@16384/20480, MRED@24576 (8*1040),
//             HT@32896 (16*33), NL@33424 (16*33); total 33952 f = 135808 B.
// ---------------------------------------------------------------------------
template <bool LAST>
__global__ __launch_bounds__(1024) void k_edge(
    const float* __restrict__ Rp, const float* __restrict__ S,
    const float* __restrict__ P, const float* __restrict__ Q,
    const uint4* __restrict__ Bfrag,
    const float* __restrict__ Wn0, const float* __restrict__ bn0,
    const float* __restrict__ Wn1, const float* __restrict__ bn1,
    const float* __restrict__ We1, const float* __restrict__ be1,
    const float* __restrict__ Wp, const float* __restrict__ Wq,
    const float* __restrict__ bp,
    float* __restrict__ h_io,
    float* __restrict__ RpW, float* __restrict__ SW,
    float* __restrict__ PW, float* __restrict__ QW,
    float* __restrict__ out, int t) {
  extern __shared__ float ldsf[];
  const int bid = blockIdx.x;
  const int b  = ((bid >> 7) << 3) | (bid & 7);   // XCD-friendly: b&7 == bid&7
  const int i0 = ((bid >> 3) & 15) << 4;
  const int tid = threadIdx.x;
  const int wv = tid >> 6, lane = tid & 63;
  const int col = lane & 15, kg = lane >> 4;

  float* HT = ldsf + 32896;
  float* NL = ldsf + 33424;

  if (tid < 512) {             // stage h tile for the node phase
    int r = tid >> 5, o = tid & 31;
    HT[r * 33 + o] = h_io[((b << 8) + i0 + r) * 32 + o];
  }

  union BU { uint4 q; bf16x8 v; };
  BU bfr[4][4];
#pragma unroll
  for (int kk = 0; kk < 4; ++kk)
#pragma unroll
    for (int nt = 0; nt < 4; ++nt)
      bfr[kk][nt].q = Bfrag[((t * 4 + kk) * 4 + nt) * 64 + lane];

  // receiver contribution (j-invariant): R'[i0+col, kk*32+kg*8 + 0..7]
  float4 rA[4][2];
  const float* rB = Rp + (size_t)((b << 8) + i0 + col) * 128 + kg * 8;
#pragma unroll
  for (int kk = 0; kk < 4; ++kk) {
    rA[kk][0] = *(const float4*)(rB + kk * 32);
    rA[kk][1] = *(const float4*)(rB + kk * 32 + 4);
  }

  // P in C-layout: row i = i0 + kg*4 + r, col o = nt*16 + col
  float pb[4][4];
#pragma unroll
  for (int nt = 0; nt < 4; ++nt)
#pragma unroll
    for (int r = 0; r < 4; ++r)
      pb[nt][r] = P[(size_t)((b << 8) + i0 + kg * 4 + r) * 64 + nt * 16 + col];

  const float* Sc = S + (size_t)(b << 8) * 128;
  const float* Qc = Q + (size_t)(b << 8) * 64;

  // cooperative chunk staging: S 32KB = 32 segs (wave: 2), Q 16KB = 16 segs (wave: 1)
  auto STAGE = [&](int c, int buf) {
    const char* gs = (const char*)(Sc + c * 64 * 128);
    char* ls = (char*)(ldsf + buf * 8192);
    int o1 = (wv * 2) * 1024 + lane * 16;
    GLD_LDS16(gs + o1, ls + o1);
    GLD_LDS16(gs + o1 + 1024, ls + o1 + 1024);
    const char* gq = (const char*)(Qc + c * 64 * 64);
    char* lq = (char*)(ldsf + 16384 + buf * 4096);
    int o3 = wv * 1024 + lane * 16;
    GLD_LDS16(gq + o3, lq + o3);
  };

  float m[4][4] = {};
  STAGE(0, 0);
  __syncthreads();   // drains vmcnt -> chunk 0 resident

  int cur = 0;
  for (int c = 0; c < 4; ++c) {
    if (c < 3) STAGE(c + 1, cur ^ 1);        // prefetch stays in flight over compute
    const float* Sb = ldsf + cur * 8192;
    const float* Qb = ldsf + 16384 + cur * 4096;
#pragma unroll
    for (int jj = 0; jj < 4; ++jj) {
      const int jl = (wv << 2) + jj;         // row in chunk, 0..63
      const float* sj = Sb + jl * 128 + kg * 8;

      BU af[4];
#pragma unroll
      for (int kk = 0; kk < 4; ++kk) {
        float4 s0 = *(const float4*)(sj + kk * 32);
        float4 s1 = *(const float4*)(sj + kk * 32 + 4);
        float4 r0 = rA[kk][0], r1 = rA[kk][1];
        unsigned u0 = cvt_pk_bf16_abs(r0.x + s0.x, r0.y + s0.y);
        unsigned u1 = cvt_pk_bf16_abs(r0.z + s0.z, r0.w + s0.w);
        unsigned u2 = cvt_pk_bf16_abs(r1.x + s1.x, r1.y + s1.y);
        unsigned u3 = cvt_pk_bf16_abs(r1.z + s1.z, r1.w + s1.w);
        af[kk].q = make_uint4(u0, u1, u2, u3);
      }

      f32x4 acc[4];
#pragma unroll
      for (int nt = 0; nt < 4; ++nt) {
        float qv = Qb[jl * 64 + nt * 16 + col];
        f32x4 cc;
        cc[0] = pb[nt][0] + qv; cc[1] = pb[nt][1] + qv;
        cc[2] = pb[nt][2] + qv; cc[3] = pb[nt][3] + qv;
        acc[nt] = cc;
      }
#pragma unroll
      for (int kk = 0; kk < 4; ++kk)
#pragma unroll
        for (int nt = 0; nt < 4; ++nt)
          acc[nt] = __builtin_amdgcn_mfma_f32_16x16x32_bf16(af[kk].v, bfr[kk][nt].v, acc[nt], 0, 0, 0);

#pragma unroll
      for (int nt = 0; nt < 4; ++nt)
#pragma unroll
        for (int r = 0; r < 4; ++r) {
          float e = acc[nt][r];
          m[nt][r] = fmaf(0.4f, fabsf(e), fmaf(0.6f, e, m[nt][r]));  // lrelu-sum
        }
    }
    __syncthreads();   // compute done for all waves + next chunk's loads drained
    cur ^= 1;
  }

  // two-stage reduce of the 16 wave-partials (8 LDS slots)
  float* mred = ldsf + 24576;
  if (wv < 8) {
#pragma unroll
    for (int nt = 0; nt < 4; ++nt)
#pragma unroll
      for (int r = 0; r < 4; ++r)
        mred[wv * 1040 + (kg * 4 + r) * 65 + nt * 16 + col] = m[nt][r];
  }
  __syncthreads();
  if (wv >= 8) {
#pragma unroll
    for (int nt = 0; nt < 4; ++nt)
#pragma unroll
      for (int r = 0; r < 4; ++r)
        mred[(wv - 8) * 1040 + (kg * 4 + r) * 65 + nt * 16 + col] += m[nt][r];
  }
  __syncthreads();
  {
    int il = tid >> 6, o = tid & 63;   // one element per thread
    float s = 0.f;
#pragma unroll
    for (int s8 = 0; s8 < 8; ++s8) s += mred[s8 * 1040 + il * 65 + o];
    mred[il * 65 + o] = s;             // mred[0..] becomes mfin[16][65]
  }
  __syncthreads();

  // node MLP layer 0
  if (tid < 512) {
    int r = tid >> 5, o = tid & 31;
    float a0 = bn0[t * 32 + o];
    const float* w0 = Wn0 + (size_t)t * 96 * 32 + o;
#pragma unroll 8
    for (int f = 0; f < 32; ++f) a0 += HT[r * 33 + f] * w0[f * 32];
#pragma unroll 8
    for (int f = 0; f < 64; ++f) a0 += mred[r * 65 + f] * w0[(32 + f) * 32];
    a0 = fmaxf(a0, 0.2f * a0);
    NL[r * 33 + o] = a0;
  }
  __syncthreads();

  // node MLP layer 1 (+ tanh on last round); h' replaces HT for the proj phase
  if (tid < 512) {
    int r = tid >> 5, o = tid & 31;
    float a1 = bn1[t * 32 + o];
    const float* w1 = Wn1 + (size_t)t * 1024 + o;
#pragma unroll 8
    for (int f = 0; f < 32; ++f) a1 += NL[r * 33 + f] * w1[f * 32];
    a1 = fmaxf(a1, 0.2f * a1);
    int gi = ((b << 8) + i0 + r) * 32 + o;
    if (LAST) out[gi] = tanhf(a1);
    else { h_io[gi] = a1; HT[r * 33 + o] = a1; }
  }

  if (!LAST) {
    __syncthreads();
    // proj for round t+1: wave wv handles row i0+wv (writes go to the WRITE set)
    const int t1 = t + 1;
    const int row = (b << 8) + i0 + wv;
    const float* We1t = We1 + t1 * 64 * 128;
    float r0 = be1[t1 * 128 + lane], r1 = be1[t1 * 128 + 64 + lane];
    float s0 = 0.f, s1 = 0.f;
    float p = bp[t1 * 64 + lane], q = 0.f;
    for (int f = 0; f < 32; ++f) {
      float hf = HT[wv * 33 + f];
      r0 += hf * We1t[f * 128 + lane];
      r1 += hf * We1t[f * 128 + 64 + lane];
      s0 += hf * We1t[(32 + f) * 128 + lane];
      s1 += hf * We1t[(32 + f) * 128 + 64 + lane];
      p  += hf * Wp[(t1 * 32 + f) * 64 + lane];
      q  += hf * Wq[(t1 * 32 + f) * 64 + lane];
    }
    RpW[row * 128 + lane] = r0;  RpW[row * 128 + 64 + lane] = r1;
    SW [row * 128 + lane] = s0;  SW [row * 128 + 64 + lane] = s1;
    PW [row * 64 + lane]  = p;   QW [row * 64 + lane]       = q;
  }
}

// ---------------------------------------------------------------------------
extern "C" void kernel_launch(void* const* d_in, const int* in_sizes, int n_in,
                              void* d_out, int out_size, void* d_ws, size_t ws_size,
                              hipStream_t stream) {
  const float* x     = (const float*)d_in[0];
  const float* W_lin = (const float*)d_in[1];
  const float* b_lin = (const float*)d_in[2];
  const float* W_in  = (const float*)d_in[3];
  const float* b_in  = (const float*)d_in[4];
  const float* We1   = (const float*)d_in[5];
  const float* be1   = (const float*)d_in[6];
  const float* We2   = (const float*)d_in[7];
  const float* be2   = (const float*)d_in[8];
  const float* Wn0   = (const float*)d_in[9];
  const float* bn0   = (const float*)d_in[10];
  const float* Wn1   = (const float*)d_in[11];
  const float* bn1   = (const float*)d_in[12];
  float* out = (float*)d_out;

  float* ws = (float*)d_ws;
  float* h   = ws;                      // 131072
  float* Rp0 = ws + 131072;             // 524288
  float* S0  = ws + 655360;             // 524288
  float* P0  = ws + 1179648;            // 262144
  float* Q0  = ws + 1441792;            // 262144
  float* Rp1 = ws + 1703936;            // 524288
  float* S1  = ws + 2228224;            // 524288
  float* P1  = ws + 2752512;            // 262144
  float* Q1  = ws + 3014656;            // 262144
  float* Wp  = ws + 3276800;            // 6144
  float* Wq  = ws + 3282944;            // 6144
  float* bp  = ws + 3289088;            // 192
  uint4* Bf  = (uint4*)(ws + 3289280);  // 3072 uint4

  float* RpS[2] = {Rp0, Rp1};
  float* SS [2] = {S0,  S1};
  float* PS [2] = {P0,  P1};
  float* QS [2] = {Q0,  Q1};

  const size_t lds_bytes = 33952 * sizeof(float);   // 135808 B

  k_setup<<<dim3(8, 3), 256, 0, stream>>>(We1, be1, We2, be2, Wp, Wq, bp, Bf);
  k_init_proj<<<1024, 256, 0, stream>>>(x, W_lin, b_lin, W_in, b_in,
                                        We1, be1, Wp, Wq, bp, h, Rp0, S0, P0, Q0);
  for (int t = 0; t < 3; ++t) {
    int rs = t & 1, wsx = rs ^ 1;
    if (t < 2)
      k_edge<false><<<256, 1024, lds_bytes, stream>>>(
          RpS[rs], SS[rs], PS[rs], QS[rs], Bf, Wn0, bn0, Wn1, bn1,
          We1, be1, Wp, Wq, bp, h,
          RpS[wsx], SS[wsx], PS[wsx], QS[wsx], nullptr, t);
    else
      k_edge<true><<<256, 1024, lds_bytes, stream>>>(
          RpS[rs], SS[rs], PS[rs], QS[rs], Bf, Wn0, bn0, Wn1, bn1,
          We1, be1, Wp, Wq, bp, h,
          nullptr, nullptr, nullptr, nullptr, out, t);
  }
}

// Round 5
// 206.254 us; speedup vs baseline: 2.3024x; 2.3024x over previous
//
#include <hip/hip_runtime.h>
#include <hip/hip_bf16.h>

// Sizes from the reference
#define B_  16
#define N_  256
#define L_  64
#define H_  32
#define HE_ 128
#define EO_ 64

typedef __attribute__((ext_vector_type(8))) short bf16x8;
typedef __attribute__((ext_vector_type(4))) float f32x4;

__device__ __forceinline__ unsigned cvt_pk_bf16(float a, float b) {
  unsigned r;
  asm("v_cvt_pk_bf16_f32 %0, %1, %2" : "=v"(r) : "v"(a), "v"(b));
  return r;
}
// abs folded as VOP3 input modifiers — saves the separate v_and per element
__device__ __forceinline__ unsigned cvt_pk_bf16_abs(float a, float b) {
  unsigned r;
  asm("v_cvt_pk_bf16_f32 %0, |%1|, |%2|" : "=v"(r) : "v"(a), "v"(b));
  return r;
}

// async global->LDS, 16B per lane; LDS dest = wave-uniform base + lane*16
// (we pass lane-linear addresses so the implicit per-lane offset matches)
#define GLD_LDS16(gp, lp)                                                        \
  __builtin_amdgcn_global_load_lds(                                              \
      (const __attribute__((address_space(1))) unsigned int*)(gp),               \
      (__attribute__((address_space(3))) unsigned int*)(lp), 16, 0, 0)

// ---------------------------------------------------------------------------
// Setup (once): Wp = 0.6*We1[:H]@We2, Wq = 0.6*We1[H:]@We2,
// bp = 0.6*be1@We2 + be2, and Bfrag = 0.4*We2 in bf16 MFMA B-fragment layout.
// grid (8,3), block 256
// ---------------------------------------------------------------------------
__global__ void k_setup(const float* __restrict__ We1, const float* __restrict__ be1,
                        const float* __restrict__ We2, const float* __restrict__ be2,
                        float* __restrict__ Wp, float* __restrict__ Wq,
                        float* __restrict__ bp, uint4* __restrict__ Bfrag) {
  const int t   = blockIdx.y;
  const int gid = blockIdx.x * 256 + threadIdx.x;   // 0..2047
  const float* We1t = We1 + t * 64 * 128;
  const float* We2t = We2 + t * 128 * 64;

  { // Wp / Wq: 32x64 outputs each
    int f = gid >> 6, o = gid & 63;
    float ap = 0.f, aq = 0.f;
    for (int k = 0; k < 128; ++k) {
      float w2 = We2t[k * 64 + o];
      ap += We1t[f * 128 + k] * w2;
      aq += We1t[(32 + f) * 128 + k] * w2;
    }
    Wp[(t * 32 + f) * 64 + o] = 0.6f * ap;
    Wq[(t * 32 + f) * 64 + o] = 0.6f * aq;
  }
  if (gid < 64) {
    float ab = be2[t * 64 + gid];
    for (int k = 0; k < 128; ++k) ab += 0.6f * be1[t * 128 + k] * We2t[k * 64 + gid];
    bp[t * 64 + gid] = ab;
  }
  // Bfrag: 1024 uint4 per t; frag map: k = kk*32 + (lane>>4)*8 + e, o = nt*16 + (lane&15)
  if (gid < 1024) {
    int u = gid;
    int kk = u >> 8, nt = (u >> 6) & 3, ln = u & 63;
    int k0 = kk * 32 + (ln >> 4) * 8, o = nt * 16 + (ln & 15);
    unsigned w[4];
#pragma unroll
    for (int p = 0; p < 4; ++p) {
      float v0 = 0.4f * We2t[(k0 + 2 * p) * 64 + o];
      float v1 = 0.4f * We2t[(k0 + 2 * p + 1) * 64 + o];
      w[p] = cvt_pk_bf16(v0, v1);
    }
    Bfrag[t * 1024 + u] = make_uint4(w[0], w[1], w[2], w[3]);
  }
}

// ---------------------------------------------------------------------------
// Init + proj(t=0), fused: h = (x@W_lin+b_lin)@W_in+b_in, then
// R' = h@We1[:H]+be1, S = h@We1[H:], P = h@Wp+bp, Q = h@Wq  (t=0, write set 0).
// grid 1024, block 256 (one wave per (b,n) row)
// ---------------------------------------------------------------------------
__global__ __launch_bounds__(256) void k_init_proj(
    const float* __restrict__ x, const float* __restrict__ W_lin,
    const float* __restrict__ b_lin, const float* __restrict__ W_in,
    const float* __restrict__ b_in,
    const float* __restrict__ We1, const float* __restrict__ be1,
    const float* __restrict__ Wp, const float* __restrict__ Wq,
    const float* __restrict__ bp,
    float* __restrict__ h, float* __restrict__ Rp, float* __restrict__ S,
    float* __restrict__ P, float* __restrict__ Q) {
  __shared__ float sm[4][64];
  __shared__ float hs[4][33];
  const int w = threadIdx.x >> 6, lane = threadIdx.x & 63;
  const int row = __builtin_amdgcn_readfirstlane(blockIdx.x * 4 + w);
  const int b = row >> 8, n = row & 255;
  float acc = b_lin[n * 64 + lane];
  const float* xb = x + b * 64;
  for (int l = 0; l < 64; ++l)
    acc += xb[l] * W_lin[l * (N_ * L_) + n * 64 + lane];
  sm[w][lane] = acc;
  __syncthreads();
  if (lane < 32) {
    float hacc = b_in[lane];
#pragma unroll 8
    for (int f = 0; f < 64; ++f) hacc += sm[w][f] * W_in[f * 32 + lane];
    h[row * 32 + lane] = hacc;
    hs[w][lane] = hacc;
  }
  __syncthreads();

  // proj for t=0, h from LDS
  float r0 = be1[lane], r1 = be1[64 + lane];
  float s0 = 0.f, s1 = 0.f;
  float p = bp[lane], q = 0.f;
  for (int f = 0; f < 32; ++f) {
    float hf = hs[w][f];
    r0 += hf * We1[f * 128 + lane];
    r1 += hf * We1[f * 128 + 64 + lane];
    s0 += hf * We1[(32 + f) * 128 + lane];
    s1 += hf * We1[(32 + f) * 128 + 64 + lane];
    p  += hf * Wp[f * 64 + lane];
    q  += hf * Wq[f * 64 + lane];
  }
  Rp[row * 128 + lane] = r0;  Rp[row * 128 + 64 + lane] = r1;
  S [row * 128 + lane] = s0;  S [row * 128 + 64 + lane] = s1;
  P [row * 64 + lane]  = p;   Q [row * 64 + lane]       = q;
}

// ---------------------------------------------------------------------------
// Fused per-round kernel: edge-MLP over ALL j + aggregate + node MLP +
// proj(t+1). grid 256 = (b, 16-row i-tile); block 512 (8 waves, 2/SIMD,
// __launch_bounds__(512,2) -> 256-VGPR budget: the R1-proven no-spill regime).
// The j-loop reads ONLY LDS: S/Q staged per 64-j chunk via global_load_lds,
// double-buffered; prefetch of chunk c+1 issued before computing chunk c.
// LDS floats: SB[2]@0/8192, QB[2]@16384/20480, MR@24576 (4*1040),
//             HT@28736 (16*33), NL@29264 (16*33); total 29792 f = 119168 B.
// ---------------------------------------------------------------------------
template <bool LAST>
__global__ __launch_bounds__(512, 2) void k_edge(
    const float* __restrict__ Rp, const float* __restrict__ S,
    const float* __restrict__ P, const float* __restrict__ Q,
    const uint4* __restrict__ Bfrag,
    const float* __restrict__ Wn0, const float* __restrict__ bn0,
    const float* __restrict__ Wn1, const float* __restrict__ bn1,
    const float* __restrict__ We1, const float* __restrict__ be1,
    const float* __restrict__ Wp, const float* __restrict__ Wq,
    const float* __restrict__ bp,
    float* __restrict__ h_io,
    float* __restrict__ RpW, float* __restrict__ SW,
    float* __restrict__ PW, float* __restrict__ QW,
    float* __restrict__ out, int t) {
  extern __shared__ float ldsf[];
  const int bid = blockIdx.x;
  const int b  = bid >> 4;
  const int i0 = (bid & 15) << 4;
  const int tid = threadIdx.x;
  const int wv = tid >> 6, lane = tid & 63;
  const int col = lane & 15, kg = lane >> 4;

  float* SB = ldsf;            // 2 x 8192  (chunk: 64 j x 128 k)
  float* QB = ldsf + 16384;    // 2 x 4096  (chunk: 64 j x 64 o)
  float* MR = ldsf + 24576;    // 4 x 1040  (16 x 65 per slot)
  float* HT = ldsf + 28736;    // 16 x 33
  float* NL = ldsf + 29264;    // 16 x 33

  { // stage h tile for the node phase (512 threads == 16x32)
    int r = tid >> 5, o = tid & 31;
    HT[r * 33 + o] = h_io[((b << 8) + i0 + r) * 32 + o];
  }

  union BU { uint4 q; bf16x8 v; };
  BU bfr[4][4];
#pragma unroll
  for (int kk = 0; kk < 4; ++kk)
#pragma unroll
    for (int nt = 0; nt < 4; ++nt)
      bfr[kk][nt].q = Bfrag[((t * 4 + kk) * 4 + nt) * 64 + lane];

  // receiver contribution (j-invariant): R'[i0+col, kk*32+kg*8 + 0..7]
  float4 rA[4][2];
  const float* rB = Rp + (size_t)((b << 8) + i0 + col) * 128 + kg * 8;
#pragma unroll
  for (int kk = 0; kk < 4; ++kk) {
    rA[kk][0] = *(const float4*)(rB + kk * 32);
    rA[kk][1] = *(const float4*)(rB + kk * 32 + 4);
  }

  // P in C-layout: row i = i0 + kg*4 + r, col o = nt*16 + col
  float pb[4][4];
#pragma unroll
  for (int nt = 0; nt < 4; ++nt)
#pragma unroll
    for (int r = 0; r < 4; ++r)
      pb[nt][r] = P[(size_t)((b << 8) + i0 + kg * 4 + r) * 64 + nt * 16 + col];

  const float* Sc = S + (size_t)(b << 8) * 128;
  const float* Qc = Q + (size_t)(b << 8) * 64;

  // cooperative chunk staging: S 32KB -> 4 KB/wave (4 segs), Q 16KB -> 2 segs
  auto STAGE = [&](int c, int buf) {
    const char* gs = (const char*)(Sc + c * 64 * 128);
    char* ls = (char*)(SB + buf * 8192);
    int o1 = wv * 4096 + lane * 16;
#pragma unroll
    for (int sgm = 0; sgm < 4; ++sgm)
      GLD_LDS16(gs + o1 + sgm * 1024, ls + o1 + sgm * 1024);
    const char* gq = (const char*)(Qc + c * 64 * 64);
    char* lq = (char*)(QB + buf * 4096);
    int o2 = wv * 2048 + lane * 16;
    GLD_LDS16(gq + o2, lq + o2);
    GLD_LDS16(gq + o2 + 1024, lq + o2 + 1024);
  };

  float m[4][4] = {};
  STAGE(0, 0);
  __syncthreads();   // drains vmcnt -> chunk 0 resident

  int cur = 0;
  for (int c = 0; c < 4; ++c) {
    if (c < 3) STAGE(c + 1, cur ^ 1);   // prefetch stays in flight over compute
    const float* Sb = SB + cur * 8192;
    const float* Qb = QB + cur * 4096;
#pragma unroll 2
    for (int jj = 0; jj < 8; ++jj) {
      const int jl = (wv << 3) + jj;    // row in chunk, 0..63
      const float* sj = Sb + jl * 128 + kg * 8;

      BU af[4];
#pragma unroll
      for (int kk = 0; kk < 4; ++kk) {
        float4 s0 = *(const float4*)(sj + kk * 32);
        float4 s1 = *(const float4*)(sj + kk * 32 + 4);
        float4 r0 = rA[kk][0], r1 = rA[kk][1];
        unsigned u0 = cvt_pk_bf16_abs(r0.x + s0.x, r0.y + s0.y);
        unsigned u1 = cvt_pk_bf16_abs(r0.z + s0.z, r0.w + s0.w);
        unsigned u2 = cvt_pk_bf16_abs(r1.x + s1.x, r1.y + s1.y);
        unsigned u3 = cvt_pk_bf16_abs(r1.z + s1.z, r1.w + s1.w);
        af[kk].q = make_uint4(u0, u1, u2, u3);
      }

      f32x4 acc[4];
#pragma unroll
      for (int nt = 0; nt < 4; ++nt) {
        float qv = Qb[jl * 64 + nt * 16 + col];
        f32x4 cc;
        cc[0] = pb[nt][0] + qv; cc[1] = pb[nt][1] + qv;
        cc[2] = pb[nt][2] + qv; cc[3] = pb[nt][3] + qv;
        acc[nt] = cc;
      }
#pragma unroll
      for (int kk = 0; kk < 4; ++kk)
#pragma unroll
        for (int nt = 0; nt < 4; ++nt)
          acc[nt] = __builtin_amdgcn_mfma_f32_16x16x32_bf16(af[kk].v, bfr[kk][nt].v, acc[nt], 0, 0, 0);

#pragma unroll
      for (int nt = 0; nt < 4; ++nt)
#pragma unroll
        for (int r = 0; r < 4; ++r) {
          float e = acc[nt][r];
          m[nt][r] = fmaf(0.4f, fabsf(e), fmaf(0.6f, e, m[nt][r]));  // lrelu-sum
        }
    }
    __syncthreads();   // all waves done + next chunk's loads drained
    cur ^= 1;
  }

  // two-stage reduce of the 8 wave-partials into 4 slots, then final sum
  if (wv < 4) {
#pragma unroll
    for (int nt = 0; nt < 4; ++nt)
#pragma unroll
      for (int r = 0; r < 4; ++r)
        MR[wv * 1040 + (kg * 4 + r) * 65 + nt * 16 + col] = m[nt][r];
  }
  __syncthreads();
  if (wv >= 4) {
#pragma unroll
    for (int nt = 0; nt < 4; ++nt)
#pragma unroll
      for (int r = 0; r < 4; ++r)
        MR[(wv - 4) * 1040 + (kg * 4 + r) * 65 + nt * 16 + col] += m[nt][r];
  }
  __syncthreads();
  for (int e = tid; e < 1024; e += 512) {
    int il = e >> 6, o = e & 63;
    float s = MR[il * 65 + o] + MR[1040 + il * 65 + o] +
              MR[2080 + il * 65 + o] + MR[3120 + il * 65 + o];
    MR[il * 65 + o] = s;       // slot 0 becomes mfin[16][65]
  }
  __syncthreads();

  // node MLP layer 0 (512 threads == 16 rows x 32 outs)
  {
    int r = tid >> 5, o = tid & 31;
    float a0 = bn0[t * 32 + o];
    const float* w0 = Wn0 + (size_t)t * 96 * 32 + o;
#pragma unroll 8
    for (int f = 0; f < 32; ++f) a0 += HT[r * 33 + f] * w0[f * 32];
#pragma unroll 8
    for (int f = 0; f < 64; ++f) a0 += MR[r * 65 + f] * w0[(32 + f) * 32];
    a0 = fmaxf(a0, 0.2f * a0);
    NL[r * 33 + o] = a0;
  }
  __syncthreads();

  // node MLP layer 1 (+ tanh on last round); h' replaces HT for the proj phase
  {
    int r = tid >> 5, o = tid & 31;
    float a1 = bn1[t * 32 + o];
    const float* w1 = Wn1 + (size_t)t * 1024 + o;
#pragma unroll 8
    for (int f = 0; f < 32; ++f) a1 += NL[r * 33 + f] * w1[f * 32];
    a1 = fmaxf(a1, 0.2f * a1);
    int gi = ((b << 8) + i0 + r) * 32 + o;
    if (LAST) out[gi] = tanhf(a1);
    else { h_io[gi] = a1; HT[r * 33 + o] = a1; }
  }

  if (!LAST) {
    __syncthreads();
    // proj for round t+1: wave wv handles rows i0+2*wv, i0+2*wv+1
    const int t1 = t + 1;
    const float* We1t = We1 + t1 * 64 * 128;
#pragma unroll
    for (int rr = wv * 2; rr < wv * 2 + 2; ++rr) {
      const int row = (b << 8) + i0 + rr;
      float r0 = be1[t1 * 128 + lane], r1 = be1[t1 * 128 + 64 + lane];
      float s0 = 0.f, s1 = 0.f;
      float p = bp[t1 * 64 + lane], q = 0.f;
      for (int f = 0; f < 32; ++f) {
        float hf = HT[rr * 33 + f];
        r0 += hf * We1t[f * 128 + lane];
        r1 += hf * We1t[f * 128 + 64 + lane];
        s0 += hf * We1t[(32 + f) * 128 + lane];
        s1 += hf * We1t[(32 + f) * 128 + 64 + lane];
        p  += hf * Wp[(t1 * 32 + f) * 64 + lane];
        q  += hf * Wq[(t1 * 32 + f) * 64 + lane];
      }
      RpW[row * 128 + lane] = r0;  RpW[row * 128 + 64 + lane] = r1;
      SW [row * 128 + lane] = s0;  SW [row * 128 + 64 + lane] = s1;
      PW [row * 64 + lane]  = p;   QW [row * 64 + lane]       = q;
    }
  }
}

// ---------------------------------------------------------------------------
extern "C" void kernel_launch(void* const* d_in, const int* in_sizes, int n_in,
                              void* d_out, int out_size, void* d_ws, size_t ws_size,
                              hipStream_t stream) {
  const float* x     = (const float*)d_in[0];
  const float* W_lin = (const float*)d_in[1];
  const float* b_lin = (const float*)d_in[2];
  const float* W_in  = (const float*)d_in[3];
  const float* b_in  = (const float*)d_in[4];
  const float* We1   = (const float*)d_in[5];
  const float* be1   = (const float*)d_in[6];
  const float* We2   = (const float*)d_in[7];
  const float* be2   = (const float*)d_in[8];
  const float* Wn0   = (const float*)d_in[9];
  const float* bn0   = (const float*)d_in[10];
  const float* Wn1   = (const float*)d_in[11];
  const float* bn1   = (const float*)d_in[12];
  float* out = (float*)d_out;

  float* ws = (float*)d_ws;
  float* h   = ws;                      // 131072
  float* Rp0 = ws + 131072;             // 524288
  float* S0  = ws + 655360;             // 524288
  float* P0  = ws + 1179648;            // 262144
  float* Q0  = ws + 1441792;            // 262144
  float* Rp1 = ws + 1703936;            // 524288
  float* S1  = ws + 2228224;            // 524288
  float* P1  = ws + 2752512;            // 262144
  float* Q1  = ws + 3014656;            // 262144
  float* Wp  = ws + 3276800;            // 6144
  float* Wq  = ws + 3282944;            // 6144
  float* bp  = ws + 3289088;            // 192
  uint4* Bf  = (uint4*)(ws + 3289280);  // 3072 uint4

  float* RpS[2] = {Rp0, Rp1};
  float* SS [2] = {S0,  S1};
  float* PS [2] = {P0,  P1};
  float* QS [2] = {Q0,  Q1};

  const size_t lds_bytes = 29792 * sizeof(float);   // 119168 B

  k_setup<<<dim3(8, 3), 256, 0, stream>>>(We1, be1, We2, be2, Wp, Wq, bp, Bf);
  k_init_proj<<<1024, 256, 0, stream>>>(x, W_lin, b_lin, W_in, b_in,
                                        We1, be1, Wp, Wq, bp, h, Rp0, S0, P0, Q0);
  for (int t = 0; t < 3; ++t) {
    int rs = t & 1, wsx = rs ^ 1;
    if (t < 2)
      k_edge<false><<<256, 512, lds_bytes, stream>>>(
          RpS[rs], SS[rs], PS[rs], QS[rs], Bf, Wn0, bn0, Wn1, bn1,
          We1, be1, Wp, Wq, bp, h,
          RpS[wsx], SS[wsx], PS[wsx], QS[wsx], nullptr, t);
    else
      k_edge<true><<<256, 512, lds_bytes, stream>>>(
          RpS[rs], SS[rs], PS[rs], QS[rs], Bf, Wn0, bn0, Wn1, bn1,
          We1, be1, Wp, Wq, bp, h,
          nullptr, nullptr, nullptr, nullptr, out, t);
  }
}